// Round 10
// baseline (1162.842 us; speedup 1.0000x reference)
//
#include <hip/hip_runtime.h>

#define DI __device__ __forceinline__

typedef __bf16 bf16x8 __attribute__((ext_vector_type(8)));
typedef float f32x4 __attribute__((ext_vector_type(4)));
typedef unsigned short u16x8 __attribute__((ext_vector_type(8)));
typedef unsigned short u16x4 __attribute__((ext_vector_type(4)));

DI float frcp(float x) { return __builtin_amdgcn_rcpf(x); }
DI float fsig(float x) { return frcp(1.0f + __expf(-x)); }
DI float ftanh(float x) { return 1.0f - 2.0f * frcp(1.0f + __expf(2.0f * x)); }

// ---------------- zero the 256-float zero-page ------------------------------
__global__ __launch_bounds__(256) void k_zero(float* __restrict__ zp) {
    zp[threadIdx.x] = 0.f;
}

// ---------------- conv 7x7 masked, 1 -> 16 ch, pad 3; out channel-last ------
__global__ __launch_bounds__(256) void k_conv(const float* __restrict__ X,
                                              const float* __restrict__ Wc,
                                              const float* __restrict__ Bc,
                                              float* __restrict__ xo) {
    int n = blockIdx.x * 256 + threadIdx.x;
    int xx = n & 63, yy = (n >> 6) & 63, b = n >> 12;
    float acc[16];
#pragma unroll
    for (int o = 0; o < 16; ++o) acc[o] = Bc[o];
    const float* Xb = X + (size_t)b * 4096;
#pragma unroll
    for (int ky = 0; ky < 4; ++ky) {
        int yi = yy + ky - 3;
        if (yi < 0) continue;
        int kxmax = (ky == 3) ? 3 : 7;
        for (int kx = 0; kx < kxmax; ++kx) {
            int xi = xx + kx - 3;
            if (xi < 0 || xi > 63) continue;
            float v = Xb[yi * 64 + xi];
#pragma unroll
            for (int o = 0; o < 16; ++o)
                acc[o] = fmaf(Wc[o * 49 + ky * 7 + kx], v, acc[o]);
        }
    }
    float4* xp = reinterpret_cast<float4*>(xo + (size_t)n * 16);
#pragma unroll
    for (int q = 0; q < 4; ++q) {
        float4 t; t.x = acc[q*4]; t.y = acc[q*4+1]; t.z = acc[q*4+2]; t.w = acc[q*4+3];
        xp[q] = t;
    }
}

// ---------------- fused diagonal LSTM scan, barrier-free --------------------
// One block per (b,dir), 4 waves, wave wv owns rows 16wv..16wv+15.
// h ring: hbuf[4 slots]; step tt reads slot tt&3 (h(tt-1)), writes (tt+1)&3.
// Intra-wave h reuse is safe by LDS FIFO order; the single cross-wave value
// (row 16wv-1) is guarded by pf/cf flags (producer/consumer step counters),
// giving a 1..3-step wave pipeline instead of a block barrier.
__global__ __launch_bounds__(256, 1) void k_scan(const float* __restrict__ Vin,
                                                 float* __restrict__ Vout,
                                                 const float* __restrict__ fIn,
                                                 const float* __restrict__ bIn,
                                                 float* __restrict__ fOut,
                                                 float* __restrict__ bOut,
                                                 const float* __restrict__ wi_all,
                                                 const float* __restrict__ w0_all,
                                                 const float* __restrict__ w1_all,
                                                 const float* __restrict__ bi_all,
                                                 int layer, int first,
                                                 const float* __restrict__ zp,
                                                 float* __restrict__ dump) {
    int dir = blockIdx.x >> 5, b = blockIdx.x & 31;
    int t = threadIdx.x;
    int wv = t >> 6;
    int l = t & 63;
    int kb = l >> 4;
    int m = l & 15;
    int r = wv * 16 + m;
    int wb_ = (layer * 2 + dir) * 1024;

    // ---- A frags: k<16 -> W1, k>=16 -> W0; lane kb holds k=kb*8..+7, split hi/lo
    const float* Wsel = (kb < 2 ? w1_all : w0_all) + wb_;
    int koff = (kb & 1) * 8;
    bf16x8 ahi[4], alo[4];
#pragma unroll
    for (int mb = 0; mb < 4; ++mb) {
        const float* wr = Wsel + (mb * 16 + m) * 16 + koff;
#pragma unroll
        for (int j = 0; j < 8; ++j) {
            float wv_ = wr[j];
            __bf16 hi = (__bf16)wv_;
            ahi[mb][j] = hi;
            alo[mb][j] = (__bf16)(wv_ - (float)hi);
        }
    }
    // ---- Wi frags for fused i2s GEMV (K-packed: kb<2 hi-plane, kb>=2 lo-plane)
    const float* Wi = wi_all + wb_;
    int cbase = (kb & 1) * 8;
    bf16x8 wihi[4], wiloz[4];
#pragma unroll
    for (int mb = 0; mb < 4; ++mb) {
        const float* wr = Wi + (mb * 16 + m) * 16 + cbase;
#pragma unroll
        for (int j = 0; j < 8; ++j) {
            float wv_ = wr[j];
            __bf16 hi = (__bf16)wv_;
            wihi[mb][j] = hi;
            wiloz[mb][j] = (kb < 2) ? (__bf16)(wv_ - (float)hi) : (__bf16)0.f;
        }
    }
    f32x4 biasv[4];
#pragma unroll
    for (int mb = 0; mb < 4; ++mb)
#pragma unroll
        for (int j = 0; j < 4; ++j)
            biasv[mb][j] = bi_all[(layer * 2 + dir) * 64 + mb * 16 + kb * 4 + j];

    // ---- LDS: 4-slot h ring x {hi,lo}, + pipeline flags
    __shared__ __align__(16) unsigned short hbuf[4][2][65 * 24];
    __shared__ unsigned pf[4];  // producer: completed-step+1 (h written)
    __shared__ unsigned cf[4];  // consumer: completed-step+1 (h read)
    for (int i = t; i < 4 * 2 * 65 * 24; i += 256) (&hbuf[0][0][0])[i] = 0;
    if (t < 4) { pf[t] = 0; cf[t] = 0; }

    volatile unsigned* pfw = pf + (wv > 0 ? wv - 1 : 0);   // watch producer
    volatile unsigned* cfn = cf + (wv < 3 ? wv + 1 : 3);   // watch consumer
    volatile unsigned* cfp = cf + wv;                       // my consumer flag
    volatile unsigned* pfp = pf + wv;                       // my producer flag

    // ---- pointers: all advance by +-1 pixel = +-16 floats = +-4 f32x4/step
    const size_t rowbase = ((size_t)b * 64 + r) * 64;
    const size_t rowbaseU = (r > 0) ? rowbase - 64 : rowbase;
    const int wimg0 = dir ? (63 + r) : (0 - r);   // wimg at w = -r
    const long st4 = dir ? -4 : 4;                // f32x4 units per step (1 pixel)
    bool fb_load = !first;
    bool b_load = fb_load && (r > 0);
    bool vlane = fb_load && (dir == 0) && (kb < 2);

    const f32x4* zp4 = (const f32x4*)zp;
    const f32x4* pX = (const f32x4*)(Vin + ((long)rowbase + wimg0) * 16 + cbase);
    const f32x4* pF = fb_load ? (const f32x4*)(fIn + ((long)rowbase + wimg0) * 16 + cbase) : zp4;
    const f32x4* pB = b_load ? (const f32x4*)(bIn + ((long)rowbaseU + wimg0) * 16 + cbase) : zp4;
    const long stF = fb_load ? st4 : 0;
    const long stB = b_load ? st4 : 0;

    float* ob = dir ? bOut : fOut;
    f32x4* dumpT = (f32x4*)(dump + (size_t)t * 16);
    f32x4* pH = (f32x4*)(ob + ((long)rowbase + wimg0) * 16 + kb * 4);
    f32x4* pV = vlane ? (f32x4*)(Vout + ((long)rowbase + wimg0) * 16 + cbase) : dumpT;
    const long stV = vlane ? st4 : 0;

    const int boff = (r + 1 - (kb >> 1)) * 24 + (kb & 1) * 8;
    const int widx = (r + 1) * 24 + kb * 4;

    float cst[4] = {0.f, 0.f, 0.f, 0.f};

    // ---- initial current-step load (tt=0: w=-r, valid only r==0)
    f32x4 xc0, xc1, fc0, fc1, bc0, bc1;
    {
        bool lv0 = (r == 0);
        const f32x4* ax = lv0 ? pX : zp4;
        const f32x4* af = lv0 ? pF : zp4;
        const f32x4* ab = lv0 ? pB : zp4;
        xc0 = ax[0]; xc1 = ax[1];
        fc0 = af[0]; fc1 = af[1];
        bc0 = ab[0]; bc1 = ab[1];
    }
    int wnt = 1 - r;  // w of next prefetch
    __syncthreads();

#define SCAN_BODY(TT, SR, SW)                                                     \
    {                                                                             \
        /* 1. advance + prefetch for step TT+1 */                                 \
        pX += st4; pF += stF; pB += stB;                                          \
        bool lv = (unsigned)wnt < 64u;                                            \
        const f32x4* ax = lv ? pX : zp4;                                          \
        const f32x4* af = lv ? pF : zp4;                                          \
        const f32x4* ab = lv ? pB : zp4;                                          \
        f32x4 xn0 = ax[0], xn1 = ax[1];                                           \
        f32x4 fn0 = af[0], fn1 = af[1];                                           \
        f32x4 bn0 = ab[0], bn1 = ab[1];                                           \
        bool sv = (unsigned)(wnt - 1) < 64u;                                      \
        /* 2. residual v + split; V-store */                                      \
        f32x4 v80 = xc0 + fc0 + bc0, v81 = xc1 + fc1 + bc1;                       \
        bf16x8 vsel;                                                              \
        _Pragma("unroll")                                                         \
        for (int j = 0; j < 4; ++j) {                                             \
            float f0v = v80[j], f1v = v81[j];                                     \
            __bf16 h0 = (__bf16)f0v, h1 = (__bf16)f1v;                            \
            vsel[j]     = (kb < 2) ? h0 : (__bf16)(f0v - (float)h0);              \
            vsel[4 + j] = (kb < 2) ? h1 : (__bf16)(f1v - (float)h1);              \
        }                                                                         \
        {                                                                         \
            f32x4* vd = sv ? pV : dumpT;                                          \
            vd[0] = v80; vd[1] = v81;                                             \
        }                                                                         \
        /* 3. acc = bias + Wi*v */                                                \
        f32x4 acc[4];                                                             \
        _Pragma("unroll")                                                         \
        for (int mb = 0; mb < 4; ++mb) acc[mb] = biasv[mb];                       \
        _Pragma("unroll")                                                         \
        for (int mb = 0; mb < 4; ++mb)                                            \
            acc[mb] = __builtin_amdgcn_mfma_f32_16x16x32_bf16(wihi[mb], vsel, acc[mb], 0, 0, 0); \
        _Pragma("unroll")                                                         \
        for (int mb = 0; mb < 4; ++mb)                                            \
            acc[mb] = __builtin_amdgcn_mfma_f32_16x16x32_bf16(wiloz[mb], vsel, acc[mb], 0, 0, 0); \
        /* 4. consumer poll, then B-frag reads from slot SR */                    \
        if (wv > 0) {                                                             \
            while (*pfw < (unsigned)(TT)) __builtin_amdgcn_s_sleep(2);            \
            __builtin_amdgcn_sched_barrier(0);                                    \
        }                                                                         \
        u16x8 bh_raw = *(const u16x8*)&hbuf[SR][0][boff];                         \
        u16x8 bl_raw = *(const u16x8*)&hbuf[SR][1][boff];                         \
        __builtin_amdgcn_sched_barrier(0);                                        \
        if (wv > 0 && l == 0) *cfp = (unsigned)(TT) + 1u;                         \
        bf16x8 bhi = __builtin_bit_cast(bf16x8, bh_raw);                          \
        bf16x8 blo = __builtin_bit_cast(bf16x8, bl_raw);                          \
        _Pragma("unroll")                                                         \
        for (int mb = 0; mb < 4; ++mb)                                            \
            acc[mb] = __builtin_amdgcn_mfma_f32_16x16x32_bf16(ahi[mb], bhi, acc[mb], 0, 0, 0); \
        _Pragma("unroll")                                                         \
        for (int mb = 0; mb < 4; ++mb)                                            \
            acc[mb] = __builtin_amdgcn_mfma_f32_16x16x32_bf16(ahi[mb], blo, acc[mb], 0, 0, 0); \
        _Pragma("unroll")                                                         \
        for (int mb = 0; mb < 4; ++mb)                                            \
            acc[mb] = __builtin_amdgcn_mfma_f32_16x16x32_bf16(alo[mb], bhi, acc[mb], 0, 0, 0); \
        /* 5. gates */                                                            \
        f32x4 hq;                                                                 \
        u16x4 hih, lol;                                                           \
        _Pragma("unroll")                                                         \
        for (int j = 0; j < 4; ++j) {                                             \
            float so = acc[0][j], sf = acc[1][j], si = acc[2][j], sg = acc[3][j]; \
            float cn = fsig(sf) * cst[j] + fsig(si) * ftanh(sg);                  \
            cst[j] = cn;                                                          \
            float hn = fsig(so) * ftanh(cn);                                      \
            hq[j] = hn;                                                           \
            __bf16 hi = (__bf16)hn;                                               \
            hih[j] = __builtin_bit_cast(unsigned short, hi);                      \
            lol[j] = __builtin_bit_cast(unsigned short, (__bf16)(hn - (float)hi)); \
        }                                                                         \
        /* 6. producer poll (ring back-pressure), h writes to slot SW */          \
        if (wv < 3) {                                                             \
            while ((int)*cfn < (TT) - 2) __builtin_amdgcn_s_sleep(2);             \
            __builtin_amdgcn_sched_barrier(0);                                    \
        }                                                                         \
        *(u16x4*)&hbuf[SW][0][widx] = hih;                                        \
        *(u16x4*)&hbuf[SW][1][widx] = lol;                                        \
        __builtin_amdgcn_sched_barrier(0);                                        \
        if (wv < 3 && l == 0) *pfp = (unsigned)(TT) + 1u;                         \
        /* 7. h store */                                                          \
        {                                                                         \
            f32x4* hd = sv ? pH : dumpT;                                          \
            hd[0] = hq;                                                           \
        }                                                                         \
        /* 8. rotate */                                                           \
        xc0 = xn0; xc1 = xn1; fc0 = fn0; fc1 = fn1; bc0 = bn0; bc1 = bn1;         \
        pH += st4; pV += stV;                                                     \
        ++wnt;                                                                    \
    }

#pragma unroll 1
    for (int it = 0; it < 32; ++it) {
        int tb = it * 4;
        SCAN_BODY(tb + 0, 0, 1)
        SCAN_BODY(tb + 1, 1, 2)
        SCAN_BODY(tb + 2, 2, 3)
        SCAN_BODY(tb + 3, 3, 0)
    }
#undef SCAN_BODY
}

// ---------------- head: residual combine + 3-layer MLP ----------------------
__global__ __launch_bounds__(256) void k_head(const float* __restrict__ x,
                                              const float* __restrict__ fwd,
                                              const float* __restrict__ bwdr,
                                              const float* __restrict__ W1,
                                              const float* __restrict__ B1,
                                              const float* __restrict__ W2,
                                              const float* __restrict__ B2,
                                              const float* __restrict__ W3,
                                              const float* __restrict__ B3,
                                              float* __restrict__ out) {
    int n = blockIdx.x * 256 + threadIdx.x;
    int r = (n >> 6) & 63;
    size_t pix = (size_t)n;
    float v[16];
    const float4* xp = reinterpret_cast<const float4*>(x + pix * 16);
#pragma unroll
    for (int q = 0; q < 4; ++q) {
        float4 t = xp[q];
        v[q*4] = t.x; v[q*4+1] = t.y; v[q*4+2] = t.z; v[q*4+3] = t.w;
    }
    const float4* fp = reinterpret_cast<const float4*>(fwd + pix * 16);
#pragma unroll
    for (int q = 0; q < 4; ++q) {
        float4 t = fp[q];
        v[q*4] += t.x; v[q*4+1] += t.y; v[q*4+2] += t.z; v[q*4+3] += t.w;
    }
    if (r > 0) {
        const float4* bp = reinterpret_cast<const float4*>(bwdr + (pix - 64) * 16);
#pragma unroll
        for (int q = 0; q < 4; ++q) {
            float4 t = bp[q];
            v[q*4] += t.x; v[q*4+1] += t.y; v[q*4+2] += t.z; v[q*4+3] += t.w;
        }
    }
    float h1[16];
#pragma unroll
    for (int o = 0; o < 16; ++o) {
        float a = B1[o];
#pragma unroll
        for (int c = 0; c < 16; ++c) a = fmaf(W1[o * 16 + c], v[c], a);
        h1[o] = fmaxf(a, 0.f);
    }
    float h2[16];
#pragma unroll
    for (int o = 0; o < 16; ++o) {
        float a = B2[o];
#pragma unroll
        for (int c = 0; c < 16; ++c) a = fmaf(W2[o * 16 + c], h1[c], a);
        h2[o] = fmaxf(a, 0.f);
    }
    float y = B3[0];
#pragma unroll
    for (int c = 0; c < 16; ++c) y = fmaf(W3[c], h2[c], y);
    out[pix] = y;
}

extern "C" void kernel_launch(void* const* d_in, const int* in_sizes, int n_in,
                              void* d_out, int out_size, void* d_ws, size_t ws_size,
                              hipStream_t stream) {
    const float* X  = (const float*)d_in[0];
    const float* cw = (const float*)d_in[1];
    const float* cb = (const float*)d_in[2];
    const float* wi = (const float*)d_in[3];
    const float* bi = (const float*)d_in[4];
    const float* w0 = (const float*)d_in[5];
    const float* w1 = (const float*)d_in[6];
    const float* W1 = (const float*)d_in[7];
    const float* B1 = (const float*)d_in[8];
    const float* W2 = (const float*)d_in[9];
    const float* B2 = (const float*)d_in[10];
    const float* W3 = (const float*)d_in[11];
    const float* B3 = (const float*)d_in[12];
    float* out = (float*)d_out;

    char* ws = (char*)d_ws;
    float* V0 = (float*)ws;                          // 8 MiB  [b][r][w][16] f32
    float* V1 = (float*)(ws + ((size_t)8 << 20));    // 8 MiB
    float* f0 = (float*)(ws + ((size_t)16 << 20));   // 8 MiB
    float* b0 = (float*)(ws + ((size_t)24 << 20));   // 8 MiB
    float* f1 = (float*)(ws + ((size_t)32 << 20));   // 8 MiB
    float* b1 = (float*)(ws + ((size_t)40 << 20));   // 8 MiB
    float* zp = (float*)(ws + ((size_t)48 << 20));            // 1 KiB zeros
    float* dump = (float*)(ws + ((size_t)48 << 20) + 65536);  // 16 KiB scratch

    k_zero<<<1, 256, 0, stream>>>(zp);
    k_conv<<<512, 256, 0, stream>>>(X, cw, cb, V0);
    for (int l = 0; l < 7; ++l) {
        const float* Vin = (l == 0) ? V0 : (((l - 1) & 1) ? V1 : V0);
        float* Vout = (l == 0) ? V1 : ((l & 1) ? V1 : V0);
        const float* fIn = ((l + 1) & 1) ? f1 : f0;
        const float* bIn = ((l + 1) & 1) ? b1 : b0;
        float* fOut = (l & 1) ? f1 : f0;
        float* bOut = (l & 1) ? b1 : b0;
        k_scan<<<64, 256, 0, stream>>>(Vin, Vout, fIn, bIn, fOut, bOut,
                                       wi, w0, w1, bi, l, l == 0 ? 1 : 0, zp, dump);
    }
    k_head<<<512, 256, 0, stream>>>(V0, f0, b0, W1, B1, W2, B2, W3, B3, out);
}